// Round 2
// baseline (69.391 us; speedup 1.0000x reference)
//
#include <hip/hip_runtime.h>

typedef __attribute__((ext_vector_type(8))) short short8;
typedef __attribute__((ext_vector_type(8))) __bf16 bf16x8;
typedef __attribute__((ext_vector_type(4))) float f32x4;
typedef __attribute__((ext_vector_type(2))) float f32x2;

union FragU { short8 s; bf16x8 b; };

#define NPOS 128
#define DI   512
#define DO   512
#define XROW (NPOS * DI)   // 65536 floats: stride between consecutive batch rows
#define OROW (NPOS * DO)   // 65536

__device__ __forceinline__ short f2bf(float f) {
  union { float f; unsigned u; } v; v.f = f;
  // round-to-nearest-even fp32 -> bf16 (inputs are finite, no NaN handling needed)
  return (short)((v.u + 0x7FFFu + ((v.u >> 16) & 1u)) >> 16);
}

// swizzled byte offset into a [128][64] bf16 LDS tile (128 B per row)
__device__ __forceinline__ int swz(int row, int kbyte) {
  return (row * 128 + kbyte) ^ ((row & 7) << 4);
}

__global__ __launch_bounds__(256, 2)
void nlinear_mfma(const float* __restrict__ xp, const float* __restrict__ wp,
                  const float* __restrict__ bp, float* __restrict__ op) {
  // XCD-friendly remap: the 8 tiles of one n stay on one XCD (nwg=1024, %8==0)
  int blk = blockIdx.x;
  int L  = ((blk & 7) << 7) + (blk >> 3);
  int n  = L >> 3;
  int mt = (L >> 2) & 1;
  int ot = L & 3;
  int mBase = mt << 7;   // batch-row base (0 or 128)
  int oBase = ot << 7;   // output-col base (0..384)

  __shared__ char ldsbuf[2 * 128 * 64 * 2];  // A tile then B tile, bf16
  char* aLds = ldsbuf;
  char* bLds = ldsbuf + 128 * 64 * 2;

  int tid  = threadIdx.x;
  int wid  = tid >> 6;
  int lane = tid & 63;
  int wm  = (wid >> 1) << 6;   // wave's m sub-tile base (0/64)
  int wn  = (wid & 1) << 6;    // wave's o sub-tile base (0/64)
  int l16 = lane & 15;
  int l4  = lane >> 4;

  // --- A staging: thread t -> row m = t>>1, k-half = (t&1)*32 (32 floats) ---
  int am  = tid >> 1;
  int akh = (tid & 1) << 5;
  const float* aSrc = xp + (size_t)(mBase + am) * XROW + n * DI + akh;

  // --- B staging (transpose): thread t -> cols {2*(t&63), +1}, k-quarter t>>6 (16 k) ---
  int o2 = tid & 63;
  int kq = tid >> 6;
  const float* bSrc = wp + ((size_t)n * DI + (kq << 4)) * DO + oBase + (o2 << 1);

  f32x4 aReg[8];
  f32x2 bReg[16];

  f32x4 acc[4][4];
  #pragma unroll
  for (int i = 0; i < 4; ++i)
    #pragma unroll
    for (int j = 0; j < 4; ++j)
      acc[i][j] = f32x4{0.f, 0.f, 0.f, 0.f};

  auto loadA = [&](int kt) {
    #pragma unroll
    for (int i = 0; i < 8; ++i)
      aReg[i] = *(const f32x4*)(aSrc + kt * 64 + i * 4);
  };
  auto loadB = [&](int kt) {
    #pragma unroll
    for (int j = 0; j < 16; ++j)
      bReg[j] = *(const f32x2*)(bSrc + (size_t)(kt * 64 + j) * DO);
  };

  auto writeA = [&]() {
    #pragma unroll
    for (int i2 = 0; i2 < 4; ++i2) {
      short8 s;
      #pragma unroll
      for (int e = 0; e < 8; ++e) {
        float f = aReg[i2 * 2 + ((e >> 2) & 1)][e & 3];
        s[e] = f2bf(f);
      }
      *(short8*)(aLds + swz(am, (akh + i2 * 8) * 2)) = s;
    }
  };

  auto writeB = [&]() {
    #pragma unroll
    for (int p = 0; p < 2; ++p) {
      int row = (o2 << 1) + p;
      #pragma unroll
      for (int i2 = 0; i2 < 2; ++i2) {
        short8 s;
        #pragma unroll
        for (int e = 0; e < 8; ++e) {
          f32x2 v = bReg[i2 * 8 + e];
          s[e] = f2bf(p ? v.y : v.x);
        }
        *(short8*)(bLds + swz(row, ((kq << 4) + i2 * 8) * 2)) = s;
      }
    }
  };

  auto compute = [&]() {
    #pragma unroll
    for (int ks = 0; ks < 2; ++ks) {
      FragU af[4], bfr[4];
      #pragma unroll
      for (int i = 0; i < 4; ++i) {
        int row = wm + i * 16 + l16;
        af[i].s = *(const short8*)(aLds + swz(row, ks * 64 + l4 * 16));
      }
      #pragma unroll
      for (int j = 0; j < 4; ++j) {
        int row = wn + j * 16 + l16;
        bfr[j].s = *(const short8*)(bLds + swz(row, ks * 64 + l4 * 16));
      }
      #pragma unroll
      for (int i = 0; i < 4; ++i)
        #pragma unroll
        for (int j = 0; j < 4; ++j)
          acc[i][j] = __builtin_amdgcn_mfma_f32_16x16x32_bf16(
              af[i].b, bfr[j].b, acc[i][j], 0, 0, 0);
    }
  };

  loadA(0); loadB(0);
  for (int kt = 0; kt < 8; ++kt) {
    __syncthreads();           // previous tile's LDS reads complete
    writeA();                  // waits on this tile's global loads via regs
    writeB();
    __syncthreads();
    if (kt < 7) { loadA(kt + 1); loadB(kt + 1); }  // prefetch overlaps MFMA
    compute();
  }

  // epilogue: D layout col = lane&15, row = (lane>>4)*4 + r  (m89-verified)
  float bi[4];
  #pragma unroll
  for (int j = 0; j < 4; ++j)
    bi[j] = bp[n * DO + oBase + wn + j * 16 + l16];

  #pragma unroll
  for (int i = 0; i < 4; ++i) {
    #pragma unroll
    for (int j = 0; j < 4; ++j) {
      #pragma unroll
      for (int r = 0; r < 4; ++r) {
        int m = wm + i * 16 + l4 * 4 + r;
        int o = oBase + wn + j * 16 + l16;
        op[(size_t)(mBase + m) * OROW + n * DO + o] = acc[i][j][r] + bi[j];
      }
    }
  }
}

extern "C" void kernel_launch(void* const* d_in, const int* in_sizes, int n_in,
                              void* d_out, int out_size, void* d_ws, size_t ws_size,
                              hipStream_t stream) {
  const float* x = (const float*)d_in[0];
  const float* w = (const float*)d_in[1];
  const float* b = (const float*)d_in[2];
  float* o = (float*)d_out;
  hipLaunchKernelGGL(nlinear_mfma, dim3(1024), dim3(256), 0, stream, x, w, b, o);
}

// Round 3
// 60.800 us; speedup vs baseline: 1.1413x; 1.1413x over previous
//
#include <hip/hip_runtime.h>

typedef __attribute__((ext_vector_type(8))) __bf16 bf16x8;
typedef __attribute__((ext_vector_type(4))) float f32x4;

#define DI   512
#define DO   512
#define XROW (128 * DI)   // floats between consecutive batch rows of x
#define OROW (128 * DO)

// A tile [128 m][64 k] bf16, 128 B/row. Reads: rows l16-spread -> (row&7) spreads 8.
__device__ __forceinline__ int swzA(int row, int kbyte) {
  return (row * 128 + kbyte) ^ ((row & 7) << 4);
}
// B tile [128 o][64 k] bf16. Writes are rows 4L+c (row&7 only 2 classes) ->
// fold row bit 2-4 in too: (row ^ (row>>2))&7 spreads writes across all 8
// 16B slots (free) while fragment reads (rows 16j+l16) stay ~2-way.
__device__ __forceinline__ int swzB(int row, int kbyte) {
  return (row * 128 + kbyte) ^ (((row ^ (row >> 2)) & 7) << 4);
}

union FragU { bf16x8 b; };

__global__ __launch_bounds__(256, 2)
void nlinear_mfma(const float* __restrict__ xp, const float* __restrict__ wp,
                  const float* __restrict__ bp, float* __restrict__ op) {
  // XCD swizzle: the 8 tiles of one n land on one XCD, co-resident (nwg=1024)
  int blk = blockIdx.x;
  int L  = ((blk & 7) << 7) + (blk >> 3);
  int n  = L >> 3;
  int mt = (L >> 2) & 1;
  int ot = L & 3;
  int mBase = mt << 7;
  int oBase = ot << 7;

  __shared__ char ldsbuf[2 * 128 * 64 * 2];  // A tile + B tile, bf16
  char* aLds = ldsbuf;
  char* bLds = ldsbuf + 128 * 64 * 2;

  int tid  = threadIdx.x;
  int wid  = tid >> 6;
  int lane = tid & 63;
  int wm  = (wid >> 1) << 6;
  int wn  = (wid & 1) << 6;
  int l16 = lane & 15;
  int l4  = lane >> 4;

  // A staging: thread t -> row m = t>>1, k-half (t&1)*32 (32 floats, 8xf32x4)
  int am  = tid >> 1;
  int akh = (tid & 1) << 5;
  const float* aSrc = xp + (size_t)(mBase + am) * XROW + n * DI + akh;

  // B staging: thread t -> o-cols [4*(t&31), +4), k-rows kg*8..+8 (8xf32x4)
  int ob = (tid & 31) << 2;
  int kg = tid >> 5;
  const float* bSrc = wp + ((size_t)n * DI + (kg << 3)) * DO + oBase + ob;

  f32x4 aReg[8];
  f32x4 bReg[8];

  f32x4 acc[4][4];
  #pragma unroll
  for (int i = 0; i < 4; ++i)
    #pragma unroll
    for (int j = 0; j < 4; ++j)
      acc[i][j] = f32x4{0.f, 0.f, 0.f, 0.f};

  auto loadA = [&](int kt) {
    #pragma unroll
    for (int i = 0; i < 8; ++i)
      aReg[i] = *(const f32x4*)(aSrc + kt * 64 + i * 4);
  };
  auto loadB = [&](int kt) {
    #pragma unroll
    for (int j = 0; j < 8; ++j)
      bReg[j] = *(const f32x4*)(bSrc + (size_t)(kt * 64 + j) * DO);
  };

  // native __bf16 casts -> compiler emits v_cvt_pk_bf16_f32 (m240)
  auto writeA = [&]() {
    #pragma unroll
    for (int i2 = 0; i2 < 4; ++i2) {
      bf16x8 v;
      #pragma unroll
      for (int e = 0; e < 8; ++e)
        v[e] = (__bf16)aReg[i2 * 2 + (e >> 2)][e & 3];
      *(bf16x8*)(aLds + swzA(am, akh * 2 + i2 * 16)) = v;
    }
  };

  auto writeB = [&]() {
    #pragma unroll
    for (int c = 0; c < 4; ++c) {
      bf16x8 v;
      #pragma unroll
      for (int j = 0; j < 8; ++j)
        v[j] = (__bf16)bReg[j][c];
      *(bf16x8*)(bLds + swzB(ob + c, kg << 4)) = v;
    }
  };

  auto compute = [&]() {
    #pragma unroll
    for (int ks = 0; ks < 2; ++ks) {
      FragU af[4], bfr[4];
      #pragma unroll
      for (int i = 0; i < 4; ++i)
        af[i].b = *(const bf16x8*)(aLds + swzA(wm + i * 16 + l16, ks * 64 + l4 * 16));
      #pragma unroll
      for (int j = 0; j < 4; ++j)
        bfr[j].b = *(const bf16x8*)(bLds + swzB(wn + j * 16 + l16, ks * 64 + l4 * 16));
      #pragma unroll
      for (int i = 0; i < 4; ++i)
        #pragma unroll
        for (int j = 0; j < 4; ++j)
          acc[i][j] = __builtin_amdgcn_mfma_f32_16x16x32_bf16(
              af[i].b, bfr[j].b, acc[i][j], 0, 0, 0);
    }
  };

  loadA(0); loadB(0);
  for (int kt = 0; kt < 8; ++kt) {
    __syncthreads();                 // prev tile's LDS reads done
    writeA();                        // vmcnt-waits this tile's loads
    writeB();
    __syncthreads();
    if (kt < 7) { loadA(kt + 1); loadB(kt + 1); }  // prefetch under MFMA
    compute();
  }

  // epilogue: D layout col = lane&15, row = (lane>>4)*4 + r (m89-verified)
  float bi[4];
  #pragma unroll
  for (int j = 0; j < 4; ++j)
    bi[j] = bp[n * DO + oBase + wn + j * 16 + l16];

  #pragma unroll
  for (int i = 0; i < 4; ++i) {
    #pragma unroll
    for (int j = 0; j < 4; ++j) {
      #pragma unroll
      for (int r = 0; r < 4; ++r) {
        int m = wm + i * 16 + l4 * 4 + r;
        int o = oBase + wn + j * 16 + l16;
        op[(size_t)(mBase + m) * OROW + n * DO + o] = acc[i][j][r] + bi[j];
      }
    }
  }
}

extern "C" void kernel_launch(void* const* d_in, const int* in_sizes, int n_in,
                              void* d_out, int out_size, void* d_ws, size_t ws_size,
                              hipStream_t stream) {
  const float* x = (const float*)d_in[0];
  const float* w = (const float*)d_in[1];
  const float* b = (const float*)d_in[2];
  float* o = (float*)d_out;
  hipLaunchKernelGGL(nlinear_mfma, dim3(1024), dim3(256), 0, stream, x, w, b, o);
}